// Round 8
// baseline (167.227 us; speedup 1.0000x reference)
//
#include <hip/hip_runtime.h>
#include <hip/hip_bf16.h>
#include <cstdint>

#define T_TOK 4096
#define D_DIM 1024
#define E_EXP 8
#define CAP   640          // int(1.25 * 4096 / 8)
#define NBIN  64
#define MAXDROP 3456
#define MT    10           // 64-row m-tiles per expert (xg granularity)

typedef __attribute__((ext_vector_type(8))) short short8;
typedef __attribute__((ext_vector_type(4))) float f32x4;

// round-to-nearest-even float -> bf16 bits
__device__ inline unsigned short f2bf(float f) {
    uint32_t u = __float_as_uint(f);
    u += 0x7fffu + ((u >> 16) & 1u);
    return (unsigned short)(u >> 16);
}

// async global->LDS DMA: per-lane global address (this lane's 16-B slice),
// wave-uniform LDS base; HW writes at ldsbase + lane*16.
__device__ inline void dma16(const void* g, void* l) {
    __builtin_amdgcn_global_load_lds(
        (const __attribute__((address_space(1))) unsigned int*)g,
        (__attribute__((address_space(3))) unsigned int*)l, 16, 0, 0);
}

// tiled bf16 images: per (tile) 8 planes g, each [64 rows][8 shorts] = 1 KB
#define WB_TILE(e, nt, kt) ((((size_t)(e) * 16 + (nt)) * 16 + (kt)) * 4096)
#define XG_TILE(e, mt, kt) ((((size_t)(e) * MT + (mt)) * 16 + (kt)) * 4096)

// ---------------- transpose-convert: W[e][k][n] fp32 -> Wb tiled bf16 ----------------
// 2048 blocks x 256, LDS 8.4 KB -> 8 blocks/CU (wave-capped)
__global__ __launch_bounds__(256) void trans_kernel(
    const float* __restrict__ W, unsigned short* __restrict__ Wb,
    float* __restrict__ ppart)
{
    __shared__ unsigned short tile[64][66];   // stride 66: 2-way banks (free)
    int bid = blockIdx.x, tid = threadIdx.x;
    if (bid == 0) { ppart[tid] = 0.f; ppart[tid + 256] = 0.f; }   // zero 512 bins

    int e  = bid >> 8;
    int kt = (bid >> 4) & 15;
    int nt = bid & 15;
    int k0 = kt * 64, n0 = nt * 64;
    const float* Wsrc = W + (size_t)e * D_DIM * D_DIM;
    #pragma unroll
    for (int p = 0; p < 4; p++) {
        int kk = p * 16 + (tid >> 4);
        int nn = (tid & 15) * 4;
        float4 v = *(const float4*)(Wsrc + (size_t)(k0 + kk) * D_DIM + n0 + nn);
        ushort4 u;
        u.x = f2bf(v.x); u.y = f2bf(v.y); u.z = f2bf(v.z); u.w = f2bf(v.w);
        *(ushort4*)&tile[kk][nn] = u;
    }
    __syncthreads();
    unsigned short* dst = Wb + WB_TILE(e, nt, kt);
    #pragma unroll
    for (int p = 0; p < 2; p++) {
        int c = tid + 256 * p;        // chunk = g*64 + n
        int g = c >> 6, n = c & 63;
        short8 v;
        #pragma unroll
        for (int z = 0; z < 8; z++) v[z] = (short)tile[g * 8 + z][n];
        *(short8*)&dst[(size_t)c * 8] = v;   // coalesced 1 KB/wave
    }
}

// ---------------- gating: 16 tokens/block (1024 thr), Wg transposed in LDS ----------------
__global__ __launch_bounds__(1024) void gate_kernel(
    const float* __restrict__ x, const float* __restrict__ Wg,
    const float* __restrict__ bg,
    int* __restrict__ top_idx, float* __restrict__ top_prob, float* __restrict__ ppart)
{
    __shared__ float WgT[8][1024];   // 32 KB
    int tid = threadIdx.x;
    {
        const float4* wr = (const float4*)(Wg + (size_t)tid * 8);
        float4 a = wr[0], bq = wr[1];
        WgT[0][tid] = a.x;  WgT[1][tid] = a.y;  WgT[2][tid] = a.z;  WgT[3][tid] = a.w;
        WgT[4][tid] = bq.x; WgT[5][tid] = bq.y; WgT[6][tid] = bq.z; WgT[7][tid] = bq.w;
    }
    __syncthreads();

    int wid  = tid >> 6;
    int lane = tid & 63;
    int t = blockIdx.x * 16 + wid;

    const float* xr = x + (size_t)t * D_DIM;
    float acc[8];
    #pragma unroll
    for (int e = 0; e < 8; e++) acc[e] = 0.f;

    #pragma unroll
    for (int ii = 0; ii < 8; ii++) {
        int da = lane + 128 * ii;
        int db = da + 64;
        float xa = xr[da];
        float xc = xr[db];
        #pragma unroll
        for (int e = 0; e < 8; e++)
            acc[e] += xa * WgT[e][da] + xc * WgT[e][db];
    }
    #pragma unroll
    for (int off = 32; off > 0; off >>= 1) {
        #pragma unroll
        for (int e = 0; e < 8; e++) acc[e] += __shfl_xor(acc[e], off, 64);
    }
    if (lane == 0) {
        float lg[8];
        #pragma unroll
        for (int e = 0; e < 8; e++) lg[e] = acc[e] + bg[e];
        float m = lg[0]; int am = 0;
        #pragma unroll
        for (int e = 1; e < 8; e++) { if (lg[e] > m) { m = lg[e]; am = e; } }
        float ex[8], s = 0.f;
        #pragma unroll
        for (int e = 0; e < 8; e++) { ex[e] = expf(lg[e] - m); s += ex[e]; }
        float inv = 1.f / s;
        top_idx[t]  = am;
        top_prob[t] = ex[am] * inv;
        int bin = (int)(blockIdx.x & (NBIN - 1));
        #pragma unroll
        for (int e = 0; e < 8; e++) atomicAdd(&ppart[bin * 8 + e], ex[e] * inv);
    }
}

// ---------------- scan: capacity dispatch + aux loss, 1 block x 1024 thr ----------------
__global__ __launch_bounds__(1024) void scan_kernel(
    const int* __restrict__ top_idx,
    int* __restrict__ tok_list, int* __restrict__ cnt,
    const float* __restrict__ ppart,
    float* __restrict__ out, float* __restrict__ out_aux)
{
    __shared__ int counts[64][8];
    __shared__ int excl[64][8];
    __shared__ int fulltot[8];
    __shared__ int droplist[MAXDROP];
    __shared__ int ndrop;

    int tid  = threadIdx.x;
    int wv   = tid >> 6;
    int lane = tid & 63;
    unsigned long long ltmask = (lane == 0) ? 0ull : ((~0ull) >> (64 - lane));

    if (tid == 0) ndrop = 0;

    int ecache[4];
    #pragma unroll
    for (int c = 0; c < 4; c++)
        ecache[c] = top_idx[(4 * wv + c) * 64 + lane];

    #pragma unroll
    for (int c = 0; c < 4; c++) {
        int chunk = 4 * wv + c;
        int e = ecache[c];
        #pragma unroll
        for (int q = 0; q < 8; q++) {
            unsigned long long mk = __ballot(e == q);
            int tot = __popcll(mk);
            if (lane == q) counts[chunk][q] = tot;
        }
    }
    __syncthreads();

    if (wv == 0) {
        #pragma unroll
        for (int q = 0; q < 8; q++) {
            int v = counts[lane][q];
            int orig = v;
            #pragma unroll
            for (int off = 1; off < 64; off <<= 1) {
                int n = __shfl_up(v, off, 64);
                if (lane >= off) v += n;
            }
            excl[lane][q] = v - orig;
            int total = __shfl(v, 63, 64);
            if (lane == 0) {
                fulltot[q] = total;
                cnt[q] = total < CAP ? total : CAP;
            }
        }
    }
    __syncthreads();

    #pragma unroll
    for (int c = 0; c < 4; c++) {
        int chunk = 4 * wv + c;
        int t = chunk * 64 + lane;
        int e = ecache[c];
        int pos = 0;
        #pragma unroll
        for (int q = 0; q < 8; q++) {
            unsigned long long mk = __ballot(e == q);
            if (e == q) pos = excl[chunk][q] + __popcll(mk & ltmask);
        }
        if (pos < CAP) {
            tok_list[e * CAP + pos] = t;
        } else {
            int di = atomicAdd(&ndrop, 1);
            droplist[di] = t;
        }
    }
    __syncthreads();

    // zero dropped rows (usually none)
    int nd = ndrop;
    int grp = tid >> 8;
    int col = (tid & 255) * 4;
    float4 z = {0.f, 0.f, 0.f, 0.f};
    for (int d = grp; d < nd; d += 4) {
        int row = droplist[d];
        *(float4*)&out[(size_t)row * D_DIM + col] = z;
    }

    // aux loss (wave 0): E * sum_e (fullcnt_e/T) * (mean_t probs_te)
    if (wv == 0) {
        float p[8];
        #pragma unroll
        for (int e = 0; e < 8; e++) p[e] = ppart[lane * 8 + e];
        #pragma unroll
        for (int off = 32; off > 0; off >>= 1) {
            #pragma unroll
            for (int e = 0; e < 8; e++) p[e] += __shfl_xor(p[e], off, 64);
        }
        if (lane == 0) {
            float s = 0.f;
            #pragma unroll
            for (int e = 0; e < 8; e++)
                s += ((float)fulltot[e] / (float)T_TOK) * (p[e] / (float)T_TOK);
            out_aux[0] = (float)E_EXP * s;
        }
    }
}

// ---------------- gather: x fp32 rows -> xg tiled bf16 [e][mt][kt][g][row][8] ----------------
__global__ __launch_bounds__(256) void gather_kernel(
    const float* __restrict__ x, const int* __restrict__ tok_list,
    const int* __restrict__ cnt, unsigned short* __restrict__ xg)
{
    int bid = blockIdx.x;              // 8 e * 10 mt * 4 ktg = 320
    int e   = bid / 40;
    int rem = bid % 40;
    int mt  = rem >> 2, ktg = rem & 3;
    int count = cnt[e];
    int m0 = mt * 64;
    if (m0 >= count) return;

    int tid = threadIdx.x;
    const int* tl = tok_list + e * CAP;

    #pragma unroll
    for (int kk = 0; kk < 4; kk++) {
        int kt = ktg * 4 + kk;
        unsigned short* dst = xg + XG_TILE(e, mt, kt);
        #pragma unroll
        for (int p = 0; p < 2; p++) {
            int c = tid + 256 * p;     // chunk = g*64 + row
            int g = c >> 6, row = c & 63;
            int gm = m0 + row;
            int tok = tl[gm < count ? gm : count - 1];
            const float* src = x + (size_t)tok * D_DIM + kt * 64 + g * 8;
            float4 v0 = *(const float4*)(src);
            float4 v1 = *(const float4*)(src + 4);
            short8 v;
            v[0] = f2bf(v0.x); v[1] = f2bf(v0.y); v[2] = f2bf(v0.z); v[3] = f2bf(v0.w);
            v[4] = f2bf(v1.x); v[5] = f2bf(v1.y); v[6] = f2bf(v1.z); v[7] = f2bf(v1.w);
            *(short8*)&dst[(size_t)c * 8] = v;   // coalesced
        }
    }
}

// ---------------- expert GEMM: 128x64x64 tiles, coalesced DMA, dbuf LDS ----------------
// 640 blocks (8e x 5mtt x 16nt), 48 KB LDS -> 3 blocks/CU, fully resident.
__global__ __launch_bounds__(256) void expert_gemm(
    const unsigned short* __restrict__ xg, const unsigned short* __restrict__ Wb,
    const float* __restrict__ bias,
    const int* __restrict__ tok_list, const int* __restrict__ cnt,
    const float* __restrict__ top_prob, float* __restrict__ out)
{
    int bid = blockIdx.x;
    int e   = bid / 80;
    int rem = bid % 80;
    int mtt = rem >> 4, nt = rem & 15;
    int count = cnt[e];
    int m0 = mtt * 128;
    if (m0 >= count) return;
    int n0 = nt * 64;

    __shared__ unsigned short Ab[2][2][8][64][8];   // 32 KB: [buf][mhalf][g][row][8]
    __shared__ unsigned short Bb[2][8][64][8];      // 16 KB

    int tid  = threadIdx.x;
    int lane = tid & 63, w = tid >> 6;
    int quad = lane >> 4, l16 = lane & 15;
    int mh = w >> 1;                  // wave m-half: rows [mh*64, mh*64+64)
    int nw = (w & 1) * 32;
    size_t lo = (size_t)lane * 8;     // this lane's 16-B slice within a plane

    const int* tl = tok_list + e * CAP;
    const unsigned short* A0 = xg + XG_TILE(e, mtt * 2, 0) + lo;
    const unsigned short* A1 = xg + XG_TILE(e, mtt * 2 + 1, 0) + lo;
    const unsigned short* B0 = Wb + WB_TILE(e, nt, 0) + lo;

    f32x4 acc[4][2];
    #pragma unroll
    for (int i = 0; i < 4; i++)
        #pragma unroll
        for (int j = 0; j < 2; j++)
            acc[i][j] = (f32x4){0.f, 0.f, 0.f, 0.f};

    // stage kt into buffer buf: 24 planes (A 16 + B 8), 6 dma16 per wave
    auto stage = [&](int kt, int buf) {
        const unsigned short* a0 = A0 + (size_t)kt * 4096;
        const unsigned short* a1 = A1 + (size_t)kt * 4096;
        const unsigned short* bb = B0 + (size_t)kt * 4096;
        #pragma unroll
        for (int d = 0; d < 6; d++) {
            int g = w + 4 * d;        // w, w+4, ..., w+20 -> covers 0..23 over 4 waves
            if (g < 8)        dma16(a0 + (size_t)g * 512,        &Ab[buf][0][g][0][0]);
            else if (g < 16)  dma16(a1 + (size_t)(g - 8) * 512,  &Ab[buf][1][g - 8][0][0]);
            else              dma16(bb + (size_t)(g - 16) * 512, &Bb[buf][g - 16][0][0]);
        }
    };

    stage(0, 0);
    int cur = 0;
    #pragma unroll 1
    for (int kt = 0; kt < 16; kt++) {
        __syncthreads();              // cur's DMA drained; prev buffer free
        if (kt + 1 < 16) stage(kt + 1, cur ^ 1);

        short8 af[2][4], bf[2][2];
        #pragma unroll
        for (int s = 0; s < 2; s++) {
            int g = s * 4 + quad;
            #pragma unroll
            for (int i = 0; i < 4; i++)
                af[s][i] = *(const short8*)&Ab[cur][mh][g][16 * i + l16][0];
            #pragma unroll
            for (int j = 0; j < 2; j++)
                bf[s][j] = *(const short8*)&Bb[cur][g][nw + 16 * j + l16][0];
        }
        #pragma unroll
        for (int s = 0; s < 2; s++)
            #pragma unroll
            for (int i = 0; i < 4; i++)
                #pragma unroll
                for (int j = 0; j < 2; j++)
                    acc[i][j] = __builtin_amdgcn_mfma_f32_16x16x32_bf16(
                        af[s][i], bf[s][j], acc[i][j], 0, 0, 0);
        cur ^= 1;
    }

    float bv[2];
    #pragma unroll
    for (int j = 0; j < 2; j++)
        bv[j] = bias[e * D_DIM + n0 + nw + 16 * j + l16];

    #pragma unroll
    for (int i = 0; i < 4; i++) {
        int rb = m0 + mh * 64 + 16 * i + quad * 4;
        #pragma unroll
        for (int r = 0; r < 4; r++) {
            int gm = rb + r;
            if (gm >= count) continue;
            int tok = tl[gm];
            float p = top_prob[tok];
            float* orow = out + (size_t)tok * D_DIM + n0 + nw + l16;
            #pragma unroll
            for (int j = 0; j < 2; j++)
                orow[16 * j] = (acc[i][j][r] + bv[j]) * p;
        }
    }
}

extern "C" void kernel_launch(void* const* d_in, const int* in_sizes, int n_in,
                              void* d_out, int out_size, void* d_ws, size_t ws_size,
                              hipStream_t stream) {
    const float* x  = (const float*)d_in[0];   // [4096,1024]
    const float* Wg = (const float*)d_in[1];   // [1024,8]
    const float* bg = (const float*)d_in[2];   // [8]
    const float* W  = (const float*)d_in[3];   // [8,1024,1024]
    const float* b  = (const float*)d_in[4];   // [8,1024]
    float* out = (float*)d_out;                // [4096*1024 + 1]

    char* ws = (char*)d_ws;                    // ~27.3 MB used
    unsigned short* Wb = (unsigned short*)(ws + 0);          // 16,777,216 B (tiled)
    unsigned short* xg = (unsigned short*)(ws + 16777216);   // 10,485,760 B (tiled)
    int*   top_idx  = (int*)(ws + 27262976);   // 16384 B
    float* top_prob = (float*)(ws + 27279360); // 16384 B
    int*   tok_list = (int*)(ws + 27295744);   // 20480 B
    int*   cnt      = (int*)(ws + 27316224);   // 32 B
    float* ppart    = (float*)(ws + 27316256); // 2048 B

    hipLaunchKernelGGL(trans_kernel, dim3(2048), dim3(256), 0, stream, W, Wb, ppart);
    hipLaunchKernelGGL(gate_kernel, dim3(T_TOK / 16), dim3(1024), 0, stream,
                       x, Wg, bg, top_idx, top_prob, ppart);
    hipLaunchKernelGGL(scan_kernel, dim3(1), dim3(1024), 0, stream,
                       top_idx, tok_list, cnt, ppart, out, out + (size_t)T_TOK * D_DIM);
    hipLaunchKernelGGL(gather_kernel, dim3(320), dim3(256), 0, stream,
                       x, tok_list, cnt, xg);
    hipLaunchKernelGGL(expert_gemm, dim3(E_EXP * 5 * 16), dim3(256), 0, stream,
                       xg, Wb, b, tok_list, cnt, top_prob, out);
}